// Round 6
// baseline (420.915 us; speedup 1.0000x reference)
//
#include <hip/hip_runtime.h>
#include <stdint.h>

typedef unsigned short ushort_t;
typedef __attribute__((ext_vector_type(8))) short bf16x8;   // 8 bf16 = 4 VGPRs
typedef __attribute__((ext_vector_type(4))) float f32x4;

__device__ __forceinline__ ushort_t f2bf(float f) {
  union { float f; uint32_t u; } v; v.f = f;
  uint32_t u = v.u;
  u += 0x7FFFu + ((u >> 16) & 1u);   // RNE
  return (ushort_t)(u >> 16);
}
__device__ __forceinline__ float bf2f(ushort_t h) {
  union { uint32_t u; float f; } v; v.u = ((uint32_t)h) << 16;
  return v.f;
}
__device__ __forceinline__ void gl2lds16(const void* g, void* l) {
  __builtin_amdgcn_global_load_lds(
      (__attribute__((address_space(1))) void*)(uintptr_t)g,
      (__attribute__((address_space(3))) void*)(uint32_t)(uintptr_t)l,
      16, 0, 0);
}

// ============ 256x128 tile, BK=32, 8-wave GEMM, 48KB LDS -> 2 blocks/CU ============
// C = A * Bt^T.  LDS per buf: A[256][32] (16KB) | B[128][32] (8KB); double-buffered
// = 48 KiB total -> TWO blocks resident per CU (vs 1 for the 128KB 256x256 kernel).
// Mechanism: two independent barrier domains per CU; block A's MFMA overlaps
// block B's LDS/stage traffic without any intra-block scheduling heroics
// (R1-R5 showed intra-block schedules can't break the 8-wave lockstep oscillation).
// Chunk-XOR swizzle (16B chunk ^= row&3; rows are 64B = 4 chunks at K=32) on both
// stage-source and ds_read -> conflict-free fragment reads.
// K-loop = verified R4 skeleton: per tile { vmcnt(0)+lgkm(0)+barrier; prefetch
// tile t+1 (3 gl2lds); read 8 frags (4 A + 4 B b128); 16 MFMA }.  Full drain each
// boundary (stage had a whole K-tile in flight; with 2 blocks/CU the drain of one
// block overlaps the other's compute) -> tail-safe with conditional prefetch.
__device__ __forceinline__ void gemm256x128(
    const ushort_t* __restrict__ A, int lda,
    const ushort_t* __restrict__ Bt, int ldb,
    int m0, int n0, int K, char* __restrict__ smem,
    f32x4 (&acc)[4][4]) {
  const int t = threadIdx.x;
  const int lane = t & 63, wid = t >> 6;
  const int wm = wid >> 1, wn = wid & 1;      // 4 M-waves x 2 N-waves (64x64 each)
  const int lr = lane & 15, lq = lane >> 4;
  const int nt = K >> 5;

  // staging: A = 16KB (2 gl2lds/thread), B = 8KB (1 gl2lds/thread); 16B chunks
  const int rowS = t >> 2;                    // 0..127
  const int kgS = (t & 3) ^ (rowS & 3);       // swizzled chunk within 64B row
  const ushort_t* a0 = A + (size_t)(m0 + rowS) * lda + kgS * 8;       // rows 0..127
  const ushort_t* a1 = a0 + (size_t)128 * lda;                        // rows 128..255
  const ushort_t* b0 = Bt + (size_t)(n0 + rowS) * ldb + kgS * 8;      // rows 0..127
  const int d0 = t * 16;

  // fragment ds_read offset within [rows][64B] plane (row = +lr, chunk = lq^(lr&3))
  const int o = lr * 64 + ((lq ^ (lr & 3)) << 4);
  const int aW = wm * 4096;                   // wave's A base: 64 rows x 64B
  const int bW = 16384 + wn * 4096;           // wave's B base

#define STAGE(tt, buf) do { \
    char* s = smem + (buf); \
    gl2lds16(a0 + (tt) * 32, s + d0); \
    gl2lds16(a1 + (tt) * 32, s + 8192 + d0); \
    gl2lds16(b0 + (tt) * 32, s + 16384 + d0); \
  } while (0)

  bf16x8 aF[4], bF[4];

  STAGE(0, 0);
  for (int tt = 0; tt < nt; ++tt) {
    asm volatile("s_waitcnt vmcnt(0) lgkmcnt(0)\n\ts_barrier" ::: "memory");
    const int cb = (tt & 1) ? 24576 : 0;
    if (tt + 1 < nt) STAGE(tt + 1, (tt & 1) ? 0 : 24576);
    const char* base = smem + cb;
    #pragma unroll
    for (int mi = 0; mi < 4; ++mi)
      aF[mi] = *(const bf16x8*)(base + aW + mi * 1024 + o);
    #pragma unroll
    for (int ni = 0; ni < 4; ++ni)
      bF[ni] = *(const bf16x8*)(base + bW + ni * 1024 + o);
    __builtin_amdgcn_s_setprio(1);
    #pragma unroll
    for (int mi = 0; mi < 4; ++mi)
      #pragma unroll
      for (int ni = 0; ni < 4; ++ni)
        acc[mi][ni] = __builtin_amdgcn_mfma_f32_16x16x32_bf16(aF[mi], bF[ni], acc[mi][ni], 0, 0, 0);
    __builtin_amdgcn_s_setprio(0);
  }
#undef STAGE
}

// ---- fused projection: X[16384][1024] @ Wt[2048][1024]^T, grid 1024 x 512thr ----
// n0 < 1024  -> Cq bf16 row-major (GATE: multiplied by gate)
// n0 >= 1024 -> K^T/V^T store via LDS-transposed, two 32KB passes (48KB smem)
template <bool GATE>
__global__ __launch_bounds__(512, 4) void proj8(
    const ushort_t* __restrict__ X, const ushort_t* __restrict__ Wt,
    ushort_t* __restrict__ Cq, ushort_t* __restrict__ Ct,
    const ushort_t* __restrict__ gate) {
  extern __shared__ char smem[];
  const int bid = blockIdx.x;
  const int xcd = bid & 7, i = bid >> 3;        // XCD owns contiguous m-slab
  const int m0 = (xcd * 8 + (i >> 4)) * 256;    // 64 m-tiles
  const int n0 = (i & 15) * 128;                // 16 n-tiles
  f32x4 acc[4][4] = {};
  gemm256x128(X, 1024, Wt, 1024, m0, n0, 1024, smem, acc);

  const int t = threadIdx.x, lane = t & 63, wid = t >> 6;
  const int wm = wid >> 1, wn = wid & 1;
  const int lr = lane & 15, lq = lane >> 4;

  if (n0 < 1024) {
    #pragma unroll
    for (int mi = 0; mi < 4; ++mi) {
      int rbase = m0 + wm * 64 + mi * 16 + lq * 4;
      #pragma unroll
      for (int ni = 0; ni < 4; ++ni) {
        int c = n0 + wn * 64 + ni * 16 + lr;
        #pragma unroll
        for (int r = 0; r < 4; ++r) {
          float v = acc[mi][ni][r];
          if constexpr (GATE) v *= bf2f(gate[(size_t)(rbase + r) * 1024 + c]);
          Cq[(size_t)(rbase + r) * 1024 + c] = f2bf(v);
        }
      }
    }
  } else {
    const int b = m0 >> 12, nseq0 = m0 & 4095;
    #pragma unroll
    for (int p = 0; p < 2; ++p) {
      __syncthreads();
      // stage C^T slice [64 d-rows][256 ns] (32KB), 16B-chunk xor swizzle
      #pragma unroll
      for (int mi = 0; mi < 4; ++mi) {
        int ns0 = wm * 64 + mi * 16 + lq * 4;       // local nseq, 4 consecutive
        int nc = ns0 >> 3, half8 = (ns0 >> 2) & 1;
        #pragma unroll
        for (int nib = 0; nib < 2; ++nib) {
          int ni = p * 2 + nib;
          int row = wn * 32 + nib * 16 + lr;        // 0..63
          ushort4 u = make_ushort4(f2bf(acc[mi][ni][0]), f2bf(acc[mi][ni][1]),
                                   f2bf(acc[mi][ni][2]), f2bf(acc[mi][ni][3]));
          *(ushort4*)(smem + row * 512 + ((nc ^ (row & 31)) * 16) + half8 * 8) = u;
        }
      }
      __syncthreads();
      #pragma unroll
      for (int j = 0; j < 4; ++j) {
        int g = j * 512 + t;
        int r = g >> 5, nc2 = g & 31;
        bf16x8 v = *(const bf16x8*)(smem + r * 512 + ((nc2 ^ (r & 31)) * 16));
        int d = n0 - 1024 + (r >> 5) * 64 + p * 32 + ((r >> 4) & 1) * 16 + (r & 15);
        *(bf16x8*)&Ct[(((size_t)(b * 1024 + d)) << 12) + nseq0 + nc2 * 8] = v;
      }
    }
  }
}

// ---- split-K KV, grid 512: XCD owns 2 z-slices; bf16 partials ----
__global__ __launch_bounds__(512, 4) void kv8(
    const ushort_t* __restrict__ VT, const ushort_t* __restrict__ KT,
    ushort_t* __restrict__ P) {
  extern __shared__ char smem[];
  const int bid = blockIdx.x;
  const int xcd = bid & 7, i = bid >> 3;        // i: 0..63
  const int z = xcd * 2 + (i >> 5);
  const int mn = i & 31;
  const int m0 = (mn >> 3) * 256, n0 = (mn & 7) * 128;
  const int b = z & 3, s = z >> 2;
  const ushort_t* A = VT + ((size_t)b << 22) + s * 1024;
  const ushort_t* Bt = KT + ((size_t)b << 22) + s * 1024;
  f32x4 acc[4][4] = {};
  gemm256x128(A, 4096, Bt, 4096, m0, n0, 1024, smem, acc);

  const int t = threadIdx.x, lane = t & 63, wid = t >> 6;
  const int wm = wid >> 1, wn = wid & 1;
  const int lr = lane & 15, lq = lane >> 4;
  ushort_t* C = P + ((size_t)z << 20);
  #pragma unroll
  for (int mi = 0; mi < 4; ++mi) {
    int rbase = m0 + wm * 64 + mi * 16 + lq * 4;
    #pragma unroll
    for (int ni = 0; ni < 4; ++ni) {
      int c = n0 + wn * 64 + ni * 16 + lr;
      #pragma unroll
      for (int r = 0; r < 4; ++r)
        C[(size_t)(rbase + r) * 1024 + c] = f2bf(acc[mi][ni][r]);
    }
  }
}

__global__ __launch_bounds__(256) void kv_reduce(const ushort_t* __restrict__ P,
                                                 ushort_t* __restrict__ KVT) {
  size_t e4 = ((size_t)blockIdx.x * 256 + threadIdx.x) * 4;  // < 4M
  int b = (int)(e4 >> 20);
  size_t j = e4 & ((1u << 20) - 1);
  float s0 = 0.f, s1 = 0.f, s2 = 0.f, s3 = 0.f;
  #pragma unroll
  for (int sp = 0; sp < 4; ++sp) {
    ushort4 v = *(const ushort4*)(P + ((size_t)(sp * 4 + b) << 20) + j);
    s0 += bf2f(v.x); s1 += bf2f(v.y); s2 += bf2f(v.z); s3 += bf2f(v.w);
  }
  *(ushort4*)&KVT[e4] = make_ushort4(f2bf(s0), f2bf(s1), f2bf(s2), f2bf(s3));
}

// ---- final: Out[m][e] = sum_d Q[m][d] * KVT[b(m)][e][d], fp32 out, grid 512 ----
__global__ __launch_bounds__(512, 4) void fin8(
    const ushort_t* __restrict__ Q, const ushort_t* __restrict__ KVT,
    float* __restrict__ Out) {
  extern __shared__ char smem[];
  const int bid = blockIdx.x;
  const int xcd = bid & 7, i = bid >> 3;        // i: 0..63
  const int m0 = (xcd * 8 + (i >> 3)) * 256;
  const int n0 = (i & 7) * 128;
  const int b = m0 >> 12;
  f32x4 acc[4][4] = {};
  gemm256x128(Q, 1024, KVT + ((size_t)b << 20), 1024, m0, n0, 1024, smem, acc);

  const int t = threadIdx.x, lane = t & 63, wid = t >> 6;
  const int wm = wid >> 1, wn = wid & 1;
  const int lr = lane & 15, lq = lane >> 4;
  #pragma unroll
  for (int mi = 0; mi < 4; ++mi) {
    int rbase = m0 + wm * 64 + mi * 16 + lq * 4;
    #pragma unroll
    for (int ni = 0; ni < 4; ++ni) {
      int c = n0 + wn * 64 + ni * 16 + lr;
      #pragma unroll
      for (int r = 0; r < 4; ++r)
        Out[(size_t)(rbase + r) * 1024 + c] = acc[mi][ni][r];
    }
  }
}

// ---- prep: 4x weight transpose+convert planes, then X fp32->bf16 ----
__global__ __launch_bounds__(256) void prep(
    const float* __restrict__ xr, const float* __restrict__ xi,
    const float* w0, const float* w1, const float* w2, const float* w3,
    ushort_t* __restrict__ xrb, ushort_t* __restrict__ xib,
    ushort_t* o0, ushort_t* o1, ushort_t* o2, ushort_t* o3) {
  const int bid = blockIdx.x;
  const int t = threadIdx.x;
  if (bid < 4096) {
    __shared__ float tile[32][33];
    const float* W; ushort_t* O;
    switch (bid >> 10) {
      case 0: W = w0; O = o0; break;
      case 1: W = w1; O = o1; break;
      case 2: W = w2; O = o2; break;
      default: W = w3; O = o3; break;
    }
    const int within = bid & 1023;
    const int bx = (within & 31) * 32, by = (within >> 5) * 32;
    const int tx = t & 31, ty = t >> 5;   // (32, 8)
    #pragma unroll
    for (int k = 0; k < 32; k += 8)
      tile[ty + k][tx] = W[(size_t)(by + ty + k) * 1024 + bx + tx];
    __syncthreads();
    #pragma unroll
    for (int k = 0; k < 32; k += 8)
      O[(size_t)(bx + ty + k) * 1024 + by + tx] = f2bf(tile[tx][ty + k]);
  } else {
    const size_t T = 16u * 1024u * 1024u;
    size_t e = ((size_t)(bid - 4096) * 256 + t) * 8;
    const float* src; ushort_t* dst;
    if (e < T) { src = xr + e; dst = xrb + e; }
    else       { src = xi + (e - T); dst = xib + (e - T); }
    float4 f0 = *(const float4*)src;
    float4 f1 = *(const float4*)(src + 4);
    ushort4 u0 = make_ushort4(f2bf(f0.x), f2bf(f0.y), f2bf(f0.z), f2bf(f0.w));
    ushort4 u1 = make_ushort4(f2bf(f1.x), f2bf(f1.y), f2bf(f1.z), f2bf(f1.w));
    *(ushort4*)dst = u0;
    *(ushort4*)(dst + 4) = u1;
  }
}

extern "C" void kernel_launch(void* const* d_in, const int* in_sizes, int n_in,
                              void* d_out, int out_size, void* d_ws, size_t ws_size,
                              hipStream_t stream) {
  const float* xr  = (const float*)d_in[0];
  const float* xi  = (const float*)d_in[1];
  const float* wqr = (const float*)d_in[2];
  const float* wqi = (const float*)d_in[3];
  const float* wk  = (const float*)d_in[4];
  const float* wv  = (const float*)d_in[5];

  char* ws = (char*)d_ws;
  const size_t MB = 1024ull * 1024ull;
  ushort_t* WtQR = (ushort_t*)(ws + 0 * MB);    // [WtQR;WtK] contiguous [2048][1024]
  ushort_t* WtK  = (ushort_t*)(ws + 2 * MB);
  ushort_t* WtQI = (ushort_t*)(ws + 4 * MB);    // [WtQI;WtV] contiguous
  ushort_t* WtV  = (ushort_t*)(ws + 6 * MB);
  ushort_t* Xrb  = (ushort_t*)(ws + 8 * MB);    // 32MB; dead after proj1 -> VT overlays
  ushort_t* Xib  = (ushort_t*)(ws + 40 * MB);   // 32MB; dead after proj2 -> KVT overlays
  ushort_t* KT   = (ushort_t*)(ws + 72 * MB);   // 32MB [4][1024][4096]
  ushort_t* Q    = (ushort_t*)(ws + 104 * MB);  // 32MB
  ushort_t* VT   = (ushort_t*)(ws + 8 * MB);    // overlay on Xrb
  ushort_t* KVT  = (ushort_t*)(ws + 40 * MB);   // overlay on Xib, 8MB
  ushort_t* QR   = (ushort_t*)d_out;            // bf16 scratch phase (32MB)
  ushort_t* KVP  = (ushort_t*)d_out;            // [16][1024][1024] bf16 = 32MB phase

  static bool inited = false;
  if (!inited) {
    inited = true;
    hipFuncSetAttribute((const void*)&proj8<false>, hipFuncAttributeMaxDynamicSharedMemorySize, 49152);
    hipFuncSetAttribute((const void*)&proj8<true>,  hipFuncAttributeMaxDynamicSharedMemorySize, 49152);
    hipFuncSetAttribute((const void*)&kv8,          hipFuncAttributeMaxDynamicSharedMemorySize, 49152);
    hipFuncSetAttribute((const void*)&fin8,         hipFuncAttributeMaxDynamicSharedMemorySize, 49152);
  }

  prep<<<20480, 256, 0, stream>>>(xr, xi, wqr, wqi, wk, wv,
                                  Xrb, Xib, WtQR, WtQI, WtK, WtV);
  proj8<false><<<1024, 512, 49152, stream>>>(Xrb, WtQR, QR, KT, nullptr);
  proj8<true><<<1024, 512, 49152, stream>>>(Xib, WtQI, Q, VT, QR);
  kv8<<<512, 512, 49152, stream>>>(VT, KT, KVP);
  kv_reduce<<<4096, 256, 0, stream>>>(KVP, KVT);
  fin8<<<512, 512, 49152, stream>>>(Q, KVT, (float*)d_out);
}

// Round 7
// 420.449 us; speedup vs baseline: 1.0011x; 1.0011x over previous
//
#include <hip/hip_runtime.h>
#include <stdint.h>

typedef unsigned short ushort_t;
typedef __attribute__((ext_vector_type(8))) short bf16x8;   // 8 bf16 = 4 VGPRs
typedef __attribute__((ext_vector_type(4))) float f32x4;

__device__ __forceinline__ ushort_t f2bf(float f) {
  union { float f; uint32_t u; } v; v.f = f;
  uint32_t u = v.u;
  u += 0x7FFFu + ((u >> 16) & 1u);   // RNE
  return (ushort_t)(u >> 16);
}
__device__ __forceinline__ float bf2f(ushort_t h) {
  union { uint32_t u; float f; } v; v.u = ((uint32_t)h) << 16;
  return v.f;
}
__device__ __forceinline__ void gl2lds16(const void* g, void* l) {
  __builtin_amdgcn_global_load_lds(
      (__attribute__((address_space(1))) void*)(uintptr_t)g,
      (__attribute__((address_space(3))) void*)(uint32_t)(uintptr_t)l,
      16, 0, 0);
}

// ============ 256x128 tile, BK=32, 8-wave GEMM, 48KB LDS -> 2 blocks/CU ============
// C = A * Bt^T.  LDS per buf: A[256][32] (16KB) | B[128][32] (8KB); double-buffered.
// BANK-CONFLICT FIX (R6 post-mortem): rows are 64B = 16 banks, so row parity
// alternates bank offset 0/16.  Chunk swizzle must use (row>>1)&3 (NOT row&3):
//   read  chunk_phys = lq ^ ((lr>>1)&3)  -> 16 rows x chunk cover all 8 bank
//   groups exactly twice = 2-way = free (m136).  R6's row&3 gave 4-way (8.65M
//   SQ_LDS_BANK_CONFLICT).  Stage side uses the matching involution.
// K-loop = verified R4 skeleton: per tile { vmcnt(0)+lgkm(0)+barrier; prefetch
// tile t+1 (3 gl2lds); read 8 frags; 16 MFMA }.  Tail-safe (conditional prefetch
// + full drain each boundary).
__device__ __forceinline__ void gemm256x128(
    const ushort_t* __restrict__ A, int lda,
    const ushort_t* __restrict__ Bt, int ldb,
    int m0, int n0, int K, char* __restrict__ smem,
    f32x4 (&acc)[4][4]) {
  const int t = threadIdx.x;
  const int lane = t & 63, wid = t >> 6;
  const int wm = wid >> 1, wn = wid & 1;      // 4 M-waves x 2 N-waves (64x64 each)
  const int lr = lane & 15, lq = lane >> 4;
  const int nt = K >> 5;

  // staging: A = 16KB (2 gl2lds/thread), B = 8KB (1 gl2lds/thread); 16B chunks
  const int rowS = t >> 2;                    // 0..127
  const int kgS = (t & 3) ^ ((t >> 3) & 3);   // chunk ^ ((row>>1)&3)  [FIXED]
  const ushort_t* a0 = A + (size_t)(m0 + rowS) * lda + kgS * 8;       // rows 0..127
  const ushort_t* a1 = a0 + (size_t)128 * lda;                        // rows 128..255
  const ushort_t* b0 = Bt + (size_t)(n0 + rowS) * ldb + kgS * 8;      // rows 0..127
  const int d0 = t * 16;

  // fragment ds_read offset: row = +lr, chunk_phys = lq ^ ((lr>>1)&3)  [FIXED]
  const int o = lr * 64 + ((lq ^ ((lr >> 1) & 3)) << 4);
  const int aW = wm * 4096;                   // wave's A base: 64 rows x 64B
  const int bW = 16384 + wn * 4096;           // wave's B base

#define STAGE(tt, buf) do { \
    char* s = smem + (buf); \
    gl2lds16(a0 + (tt) * 32, s + d0); \
    gl2lds16(a1 + (tt) * 32, s + 8192 + d0); \
    gl2lds16(b0 + (tt) * 32, s + 16384 + d0); \
  } while (0)

  bf16x8 aF[4], bF[4];

  STAGE(0, 0);
  for (int tt = 0; tt < nt; ++tt) {
    asm volatile("s_waitcnt vmcnt(0) lgkmcnt(0)\n\ts_barrier" ::: "memory");
    const int cb = (tt & 1) ? 24576 : 0;
    if (tt + 1 < nt) STAGE(tt + 1, (tt & 1) ? 0 : 24576);
    const char* base = smem + cb;
    #pragma unroll
    for (int mi = 0; mi < 4; ++mi)
      aF[mi] = *(const bf16x8*)(base + aW + mi * 1024 + o);
    #pragma unroll
    for (int ni = 0; ni < 4; ++ni)
      bF[ni] = *(const bf16x8*)(base + bW + ni * 1024 + o);
    __builtin_amdgcn_s_setprio(1);
    #pragma unroll
    for (int mi = 0; mi < 4; ++mi)
      #pragma unroll
      for (int ni = 0; ni < 4; ++ni)
        acc[mi][ni] = __builtin_amdgcn_mfma_f32_16x16x32_bf16(aF[mi], bF[ni], acc[mi][ni], 0, 0, 0);
    __builtin_amdgcn_s_setprio(0);
  }
#undef STAGE
}

// ---- fused projection: X[16384][1024] @ Wt[2048][1024]^T, grid 1024 x 512thr ----
// n0 < 1024  -> Cq bf16 row-major (GATE: multiplied by gate)
// n0 >= 1024 -> K^T/V^T store via LDS-transposed, two 32KB passes (48KB smem)
template <bool GATE>
__global__ __launch_bounds__(512, 4) void proj8(
    const ushort_t* __restrict__ X, const ushort_t* __restrict__ Wt,
    ushort_t* __restrict__ Cq, ushort_t* __restrict__ Ct,
    const ushort_t* __restrict__ gate) {
  extern __shared__ char smem[];
  const int bid = blockIdx.x;
  const int xcd = bid & 7, i = bid >> 3;        // XCD owns contiguous m-slab
  const int m0 = (xcd * 8 + (i >> 4)) * 256;    // 64 m-tiles
  const int n0 = (i & 15) * 128;                // 16 n-tiles
  f32x4 acc[4][4] = {};
  gemm256x128(X, 1024, Wt, 1024, m0, n0, 1024, smem, acc);

  const int t = threadIdx.x, lane = t & 63, wid = t >> 6;
  const int wm = wid >> 1, wn = wid & 1;
  const int lr = lane & 15, lq = lane >> 4;

  if (n0 < 1024) {
    #pragma unroll
    for (int mi = 0; mi < 4; ++mi) {
      int rbase = m0 + wm * 64 + mi * 16 + lq * 4;
      #pragma unroll
      for (int ni = 0; ni < 4; ++ni) {
        int c = n0 + wn * 64 + ni * 16 + lr;
        #pragma unroll
        for (int r = 0; r < 4; ++r) {
          float v = acc[mi][ni][r];
          if constexpr (GATE) v *= bf2f(gate[(size_t)(rbase + r) * 1024 + c]);
          Cq[(size_t)(rbase + r) * 1024 + c] = f2bf(v);
        }
      }
    }
  } else {
    const int b = m0 >> 12, nseq0 = m0 & 4095;
    #pragma unroll
    for (int p = 0; p < 2; ++p) {
      __syncthreads();
      // stage C^T slice [64 d-rows][256 ns] (32KB), 16B-chunk xor swizzle
      #pragma unroll
      for (int mi = 0; mi < 4; ++mi) {
        int ns0 = wm * 64 + mi * 16 + lq * 4;       // local nseq, 4 consecutive
        int nc = ns0 >> 3, half8 = (ns0 >> 2) & 1;
        #pragma unroll
        for (int nib = 0; nib < 2; ++nib) {
          int ni = p * 2 + nib;
          int row = wn * 32 + nib * 16 + lr;        // 0..63
          ushort4 u = make_ushort4(f2bf(acc[mi][ni][0]), f2bf(acc[mi][ni][1]),
                                   f2bf(acc[mi][ni][2]), f2bf(acc[mi][ni][3]));
          *(ushort4*)(smem + row * 512 + ((nc ^ (row & 31)) * 16) + half8 * 8) = u;
        }
      }
      __syncthreads();
      #pragma unroll
      for (int j = 0; j < 4; ++j) {
        int g = j * 512 + t;
        int r = g >> 5, nc2 = g & 31;
        bf16x8 v = *(const bf16x8*)(smem + r * 512 + ((nc2 ^ (r & 31)) * 16));
        int d = n0 - 1024 + (r >> 5) * 64 + p * 32 + ((r >> 4) & 1) * 16 + (r & 15);
        *(bf16x8*)&Ct[(((size_t)(b * 1024 + d)) << 12) + nseq0 + nc2 * 8] = v;
      }
    }
  }
}

// ---- split-K KV, grid 512: XCD owns 2 z-slices; bf16 partials ----
__global__ __launch_bounds__(512, 4) void kv8(
    const ushort_t* __restrict__ VT, const ushort_t* __restrict__ KT,
    ushort_t* __restrict__ P) {
  extern __shared__ char smem[];
  const int bid = blockIdx.x;
  const int xcd = bid & 7, i = bid >> 3;        // i: 0..63
  const int z = xcd * 2 + (i >> 5);
  const int mn = i & 31;
  const int m0 = (mn >> 3) * 256, n0 = (mn & 7) * 128;
  const int b = z & 3, s = z >> 2;
  const ushort_t* A = VT + ((size_t)b << 22) + s * 1024;
  const ushort_t* Bt = KT + ((size_t)b << 22) + s * 1024;
  f32x4 acc[4][4] = {};
  gemm256x128(A, 4096, Bt, 4096, m0, n0, 1024, smem, acc);

  const int t = threadIdx.x, lane = t & 63, wid = t >> 6;
  const int wm = wid >> 1, wn = wid & 1;
  const int lr = lane & 15, lq = lane >> 4;
  ushort_t* C = P + ((size_t)z << 20);
  #pragma unroll
  for (int mi = 0; mi < 4; ++mi) {
    int rbase = m0 + wm * 64 + mi * 16 + lq * 4;
    #pragma unroll
    for (int ni = 0; ni < 4; ++ni) {
      int c = n0 + wn * 64 + ni * 16 + lr;
      #pragma unroll
      for (int r = 0; r < 4; ++r)
        C[(size_t)(rbase + r) * 1024 + c] = f2bf(acc[mi][ni][r]);
    }
  }
}

__global__ __launch_bounds__(256) void kv_reduce(const ushort_t* __restrict__ P,
                                                 ushort_t* __restrict__ KVT) {
  size_t e4 = ((size_t)blockIdx.x * 256 + threadIdx.x) * 4;  // < 4M
  int b = (int)(e4 >> 20);
  size_t j = e4 & ((1u << 20) - 1);
  float s0 = 0.f, s1 = 0.f, s2 = 0.f, s3 = 0.f;
  #pragma unroll
  for (int sp = 0; sp < 4; ++sp) {
    ushort4 v = *(const ushort4*)(P + ((size_t)(sp * 4 + b) << 20) + j);
    s0 += bf2f(v.x); s1 += bf2f(v.y); s2 += bf2f(v.z); s3 += bf2f(v.w);
  }
  *(ushort4*)&KVT[e4] = make_ushort4(f2bf(s0), f2bf(s1), f2bf(s2), f2bf(s3));
}

// ---- final: Out[m][e] = sum_d Q[m][d] * KVT[b(m)][e][d], fp32 out, grid 512 ----
__global__ __launch_bounds__(512, 4) void fin8(
    const ushort_t* __restrict__ Q, const ushort_t* __restrict__ KVT,
    float* __restrict__ Out) {
  extern __shared__ char smem[];
  const int bid = blockIdx.x;
  const int xcd = bid & 7, i = bid >> 3;        // i: 0..63
  const int m0 = (xcd * 8 + (i >> 3)) * 256;
  const int n0 = (i & 7) * 128;
  const int b = m0 >> 12;
  f32x4 acc[4][4] = {};
  gemm256x128(Q, 1024, KVT + ((size_t)b << 20), 1024, m0, n0, 1024, smem, acc);

  const int t = threadIdx.x, lane = t & 63, wid = t >> 6;
  const int wm = wid >> 1, wn = wid & 1;
  const int lr = lane & 15, lq = lane >> 4;
  #pragma unroll
  for (int mi = 0; mi < 4; ++mi) {
    int rbase = m0 + wm * 64 + mi * 16 + lq * 4;
    #pragma unroll
    for (int ni = 0; ni < 4; ++ni) {
      int c = n0 + wn * 64 + ni * 16 + lr;
      #pragma unroll
      for (int r = 0; r < 4; ++r)
        Out[(size_t)(rbase + r) * 1024 + c] = acc[mi][ni][r];
    }
  }
}

// ---- prep: 4x weight transpose+convert planes, then X fp32->bf16 ----
__global__ __launch_bounds__(256) void prep(
    const float* __restrict__ xr, const float* __restrict__ xi,
    const float* w0, const float* w1, const float* w2, const float* w3,
    ushort_t* __restrict__ xrb, ushort_t* __restrict__ xib,
    ushort_t* o0, ushort_t* o1, ushort_t* o2, ushort_t* o3) {
  const int bid = blockIdx.x;
  const int t = threadIdx.x;
  if (bid < 4096) {
    __shared__ float tile[32][33];
    const float* W; ushort_t* O;
    switch (bid >> 10) {
      case 0: W = w0; O = o0; break;
      case 1: W = w1; O = o1; break;
      case 2: W = w2; O = o2; break;
      default: W = w3; O = o3; break;
    }
    const int within = bid & 1023;
    const int bx = (within & 31) * 32, by = (within >> 5) * 32;
    const int tx = t & 31, ty = t >> 5;   // (32, 8)
    #pragma unroll
    for (int k = 0; k < 32; k += 8)
      tile[ty + k][tx] = W[(size_t)(by + ty + k) * 1024 + bx + tx];
    __syncthreads();
    #pragma unroll
    for (int k = 0; k < 32; k += 8)
      O[(size_t)(bx + ty + k) * 1024 + by + tx] = f2bf(tile[tx][ty + k]);
  } else {
    const size_t T = 16u * 1024u * 1024u;
    size_t e = ((size_t)(bid - 4096) * 256 + t) * 8;
    const float* src; ushort_t* dst;
    if (e < T) { src = xr + e; dst = xrb + e; }
    else       { src = xi + (e - T); dst = xib + (e - T); }
    float4 f0 = *(const float4*)src;
    float4 f1 = *(const float4*)(src + 4);
    ushort4 u0 = make_ushort4(f2bf(f0.x), f2bf(f0.y), f2bf(f0.z), f2bf(f0.w));
    ushort4 u1 = make_ushort4(f2bf(f1.x), f2bf(f1.y), f2bf(f1.z), f2bf(f1.w));
    *(ushort4*)dst = u0;
    *(ushort4*)(dst + 4) = u1;
  }
}

extern "C" void kernel_launch(void* const* d_in, const int* in_sizes, int n_in,
                              void* d_out, int out_size, void* d_ws, size_t ws_size,
                              hipStream_t stream) {
  const float* xr  = (const float*)d_in[0];
  const float* xi  = (const float*)d_in[1];
  const float* wqr = (const float*)d_in[2];
  const float* wqi = (const float*)d_in[3];
  const float* wk  = (const float*)d_in[4];
  const float* wv  = (const float*)d_in[5];

  char* ws = (char*)d_ws;
  const size_t MB = 1024ull * 1024ull;
  ushort_t* WtQR = (ushort_t*)(ws + 0 * MB);    // [WtQR;WtK] contiguous [2048][1024]
  ushort_t* WtK  = (ushort_t*)(ws + 2 * MB);
  ushort_t* WtQI = (ushort_t*)(ws + 4 * MB);    // [WtQI;WtV] contiguous
  ushort_t* WtV  = (ushort_t*)(ws + 6 * MB);
  ushort_t* Xrb  = (ushort_t*)(ws + 8 * MB);    // 32MB; dead after proj1 -> VT overlays
  ushort_t* Xib  = (ushort_t*)(ws + 40 * MB);   // 32MB; dead after proj2 -> KVT overlays
  ushort_t* KT   = (ushort_t*)(ws + 72 * MB);   // 32MB [4][1024][4096]
  ushort_t* Q    = (ushort_t*)(ws + 104 * MB);  // 32MB
  ushort_t* VT   = (ushort_t*)(ws + 8 * MB);    // overlay on Xrb
  ushort_t* KVT  = (ushort_t*)(ws + 40 * MB);   // overlay on Xib, 8MB
  ushort_t* QR   = (ushort_t*)d_out;            // bf16 scratch phase (32MB)
  ushort_t* KVP  = (ushort_t*)d_out;            // [16][1024][1024] bf16 = 32MB phase

  static bool inited = false;
  if (!inited) {
    inited = true;
    hipFuncSetAttribute((const void*)&proj8<false>, hipFuncAttributeMaxDynamicSharedMemorySize, 49152);
    hipFuncSetAttribute((const void*)&proj8<true>,  hipFuncAttributeMaxDynamicSharedMemorySize, 49152);
    hipFuncSetAttribute((const void*)&kv8,          hipFuncAttributeMaxDynamicSharedMemorySize, 49152);
    hipFuncSetAttribute((const void*)&fin8,         hipFuncAttributeMaxDynamicSharedMemorySize, 49152);
  }

  prep<<<20480, 256, 0, stream>>>(xr, xi, wqr, wqi, wk, wv,
                                  Xrb, Xib, WtQR, WtQI, WtK, WtV);
  proj8<false><<<1024, 512, 49152, stream>>>(Xrb, WtQR, QR, KT, nullptr);
  proj8<true><<<1024, 512, 49152, stream>>>(Xib, WtQI, Q, VT, QR);
  kv8<<<512, 512, 49152, stream>>>(VT, KT, KVP);
  kv_reduce<<<4096, 256, 0, stream>>>(KVP, KVT);
  fin8<<<512, 512, 49152, stream>>>(Q, KVT, (float*)d_out);
}